// Round 4
// baseline (347.408 us; speedup 1.0000x reference)
//
#include <hip/hip_runtime.h>
#include <hip/hip_bf16.h>

#define DEG        16
#define IN_FEATS   256
#define NUM_HEADS  4
#define OUT_FEATS  64
#define HF         256
#define NEG_SLOPE  0.2f

#define CPITCH 264     // 256 + 8 (epilogue store-transpose pitch)

typedef __attribute__((ext_vector_type(8))) short  short8;
typedef __attribute__((ext_vector_type(4))) float  floatx4;
typedef unsigned short ushortT;

__device__ __forceinline__ unsigned short f2bf(float f) {
    union { float f; unsigned u; } v; v.f = f;
    unsigned r = v.u + 0x7fffu + ((v.u >> 16) & 1u);   // round-to-nearest-even
    return (unsigned short)(r >> 16);
}
// bf16 unpack: guaranteed 1 VALU each (shift / and)
__device__ __forceinline__ float bf_lo(unsigned u) {
    union { unsigned x; float f; } v; v.x = u << 16; return v.f;
}
__device__ __forceinline__ float bf_hi(unsigned u) {
    union { unsigned x; float f; } v; v.x = u & 0xffff0000u; return v.f;
}
// packed fp32x2 -> bf16x2 (manual RTNE pack; verified absmax since round 2)
__device__ __forceinline__ unsigned cvt2(float lo, float hi) {
    return (unsigned)f2bf(lo) | ((unsigned)f2bf(hi) << 16);
}

// ---------------------------------------------------------------------------
// Kernel 0: Wt[n][k] = bf16(W[k][n])  (256x256, tiny)
// ---------------------------------------------------------------------------
__global__ __launch_bounds__(256) void conv_wt(
    const float* __restrict__ W, ushortT* __restrict__ Wt)
{
    int n = blockIdx.x;
    int k = threadIdx.x;
    Wt[n * 256 + k] = f2bf(W[k * 256 + n]);
}

// ---------------------------------------------------------------------------
// Kernel 1: h = feat @ W via MFMA bf16 (BYTE-IDENTICAL to verified version).
// ---------------------------------------------------------------------------
__global__ __launch_bounds__(256, 3) void gat_gemm_fused(
    const float* __restrict__ feat,           // fp32 [M,256]
    const ushortT* __restrict__ Bt,           // Wt bf16 [n=256][k=256]
    const float* __restrict__ attn_l,         // [256]
    const float* __restrict__ attn_r,         // [256]
    ushortT* __restrict__ Hb,                 // h bf16 [M,256]
    float* __restrict__ arow,                 // [M,4]
    float* __restrict__ acol,                 // [M,4]
    int M)
{
    // As: 64 rows x 32 chunks x 16B = 32 KB (XOR-swizzled). Cs overlays.
    __shared__ __align__(16) ushortT SMEM[64 * CPITCH];
    ushortT* As = SMEM;
    ushortT* Cs = SMEM;

    const int tid  = threadIdx.x;
    const int wave = tid >> 6;       // == head
    const int lane = tid & 63;
    const int l15  = lane & 15;
    const int quad = lane >> 4;
    const int rowBase = blockIdx.x * 64;

    // ---- Prefetch B for ks=0 (independent of LDS staging).
    short8 bbuf[2][4];
    #pragma unroll
    for (int ni = 0; ni < 4; ++ni)
        bbuf[0][ni] = *(const short8*)&Bt[(wave * 64 + ni * 16 + l15) * 256 + quad * 8];

    // ---- Stage A: 64 rows x 256 cols fp32 -> bf16 swizzled LDS.
    #pragma unroll
    for (int pass = 0; pass < 2; ++pass) {
        float4 v[8];
        #pragma unroll
        for (int i = 0; i < 8; ++i) {
            int id  = pass * 2048 + i * 256 + tid;   // flat float4 index
            int row = id >> 6;                        // 64 float4 per row
            int c4  = id & 63;
            int gr  = rowBase + row; if (gr > M - 1) gr = M - 1;
            v[i] = *(const float4*)&feat[(size_t)gr * 256 + c4 * 4];
        }
        #pragma unroll
        for (int i = 0; i < 8; ++i) {
            int id   = pass * 2048 + i * 256 + tid;
            int row  = id >> 6;
            int c4   = id & 63;
            int cg   = c4 >> 1;                       // 16B chunk col (0..31)
            int half = c4 & 1;
            uint2 w = make_uint2(cvt2(v[i].x, v[i].y), cvt2(v[i].z, v[i].w));
            *(uint2*)&As[row * 256 + ((cg ^ (row & 7)) << 3) + half * 4] = w;
        }
    }

    __syncthreads();

    floatx4 acc[4][4] = {};

    #pragma unroll
    for (int ks = 0; ks < 8; ++ks) {
        if (ks < 7) {
            #pragma unroll
            for (int ni = 0; ni < 4; ++ni)
                bbuf[(ks + 1) & 1][ni] = *(const short8*)
                    &Bt[(wave * 64 + ni * 16 + l15) * 256 + (ks + 1) * 32 + quad * 8];
        }
        short8 af[4];
        #pragma unroll
        for (int mi = 0; mi < 4; ++mi) {
            int row = mi * 16 + l15;
            int q   = ks * 4 + quad;
            int cst = q ^ (row & 7);
            af[mi] = *(const short8*)&As[row * 256 + cst * 8];
        }
        #pragma unroll
        for (int mi = 0; mi < 4; ++mi)
            #pragma unroll
            for (int ni = 0; ni < 4; ++ni)
                acc[mi][ni] = __builtin_amdgcn_mfma_f32_16x16x32_bf16(
                    af[mi], bbuf[ks & 1][ni], acc[mi][ni], 0, 0, 0);
    }

    // ---- Epilogue A: attention scores (wave == head).
    float al[4], ar[4];
    #pragma unroll
    for (int ni = 0; ni < 4; ++ni) {
        al[ni] = attn_l[wave * 64 + ni * 16 + l15];
        ar[ni] = attn_r[wave * 64 + ni * 16 + l15];
    }
    #pragma unroll
    for (int mi = 0; mi < 4; ++mi) {
        #pragma unroll
        for (int reg = 0; reg < 4; ++reg) {
            float pl = 0.f, pr = 0.f;
            #pragma unroll
            for (int ni = 0; ni < 4; ++ni) {
                pl = fmaf(acc[mi][ni][reg], al[ni], pl);
                pr = fmaf(acc[mi][ni][reg], ar[ni], pr);
            }
            #pragma unroll
            for (int off = 8; off >= 1; off >>= 1) {
                pl += __shfl_xor(pl, off, 64);   // stays within 16-lane quad
                pr += __shfl_xor(pr, off, 64);
            }
            if (l15 == 0) {
                int gr = rowBase + mi * 16 + quad * 4 + reg;
                if (gr < M) {
                    arow[gr * NUM_HEADS + wave] = pl;
                    acol[gr * NUM_HEADS + wave] = pr;
                }
            }
        }
    }

    __syncthreads();   // all As reads complete before Cs overlay

    // ---- Epilogue B: h -> bf16, coalesced row-major store via LDS transpose.
    #pragma unroll
    for (int mi = 0; mi < 4; ++mi)
        #pragma unroll
        for (int ni = 0; ni < 4; ++ni)
            #pragma unroll
            for (int reg = 0; reg < 4; ++reg)
                Cs[(mi * 16 + quad * 4 + reg) * CPITCH + wave * 64 + ni * 16 + l15] =
                    f2bf(acc[mi][ni][reg]);
    __syncthreads();

    #pragma unroll
    for (int i = 0; i < 8; ++i) {
        int f  = tid + 256 * i;
        int r  = f >> 5;
        int c8 = (f & 31) << 3;
        int gr = rowBase + r;
        if (gr < M) {
            uint4 v = *(const uint4*)&Cs[r * CPITCH + c8];
            *(uint4*)&Hb[(size_t)gr * HF + c8] = v;
        }
    }
}

// ---------------------------------------------------------------------------
// Kernel 2 (v6b): PERSISTENT GRID-STRIDE, 3-STAGE NODE PIPELINE.
// (v6 failed to compile: __builtin_nontemporal_store rejects HIP_vector_type
// float4; fixed by using the clang ext_vector floatx4 for the store.)
// Rationale (round-2 theory): occupancy 43% with nothing saturated ->
// block-churn starvation.  1792 persistent blocks (7/CU via launch_bounds),
// each wave grid-strides over ~7 nodes; per iteration prefetch
// col_ind[n+2NW] and scores[n+NW] while computing node n -> ~1 exposed
// memory round per node.  out stores nontemporal (pure streaming; stop
// evicting Hb gather lines from L2).
// Softmax math and lane mappings unchanged (verified v4/v5).
// ---------------------------------------------------------------------------
__global__ __launch_bounds__(256, 7) void gat_aggregate6(
    const ushortT* __restrict__ Hb,          // bf16 [N,256]
    const float* __restrict__ arow,          // [N,4]
    const float* __restrict__ acol,          // [N,4]
    const int* __restrict__ col_ind,         // [N*16]
    float* __restrict__ out,                 // [N,256] fp32
    int N, int NW)                            // NW = gridDim.x * 4 (total waves)
{
    const int tid  = threadIdx.x;
    const int wave = tid >> 6;
    const int lane = tid & 63;

    const int j16  = lane & 15;              // edge slot (softmax phase)
    const int hd16 = lane >> 4;              // head (softmax phase)
    const int l32     = lane & 31;           // feat chunk (agg phase)
    const int half    = lane >> 5;           // even/odd edge half
    const int headSel = (l32 >> 3) << 4;     // head*16 for alpha pull

    int n = blockIdx.x * 4 + wave;
    if (n >= N) return;

    // ---- Prologue: node n loads + node n+NW col_ind prefetch.
    int srcCur = col_ind[n * DEG + j16];
    int n1g    = n + NW;
    int srcNext = col_ind[((n1g < N) ? n1g : n) * DEG + j16];
    float arCur = arow[n * NUM_HEADS + hd16];
    float acCur = acol[srcCur * NUM_HEADS + hd16];

    while (n < N) {
        const int n1 = n + NW;
        const int n2 = n1 + NW;

        // S1: prefetch col_ind for n+2*NW (wave-uniform branch)
        int srcN2 = srcNext;
        if (n2 < N) srcN2 = col_ind[n2 * DEG + j16];

        // S2: prefetch scores for n+NW (srcNext loaded one iteration ago)
        float arNext = arCur, acNext = acCur;
        if (n1 < N) {
            arNext = arow[n1 * NUM_HEADS + hd16];
            acNext = acol[srcNext * NUM_HEADS + hd16];
        }

        // S3: softmax for node n (all operands already resident)
        float e = arCur + acCur;
        e = (e > 0.f) ? e : NEG_SLOPE * e;
        float m = e;
        #pragma unroll
        for (int off = 8; off >= 1; off >>= 1)
            m = fmaxf(m, __shfl_xor(m, off, 16));
        float ex = __expf(e - m);
        float s = ex;
        #pragma unroll
        for (int off = 8; off >= 1; off >>= 1)
            s += __shfl_xor(s, off, 16);
        float alpha = ex / s;                // alpha[head=hd16][edge=j16]

        // S4: dual-edge gather + FMA for node n.
        int   sj[8];
        float av[8];
        #pragma unroll
        for (int j = 0; j < 8; ++j) {
            int ep = (j << 1) + half;                     // edge 0..15
            sj[j] = __shfl(srcCur, ep, 64);
            av[j] = __shfl(alpha, headSel + ep, 64);
        }
        uint4 v[8];
        #pragma unroll
        for (int j = 0; j < 8; ++j)
            v[j] = *(const uint4*)&Hb[(size_t)sj[j] * HF + l32 * 8];

        __builtin_amdgcn_sched_barrier(0);   // keep all loads above the FMAs

        float acc[8] = {};
        #pragma unroll
        for (int j = 0; j < 8; ++j) {
            acc[0] = fmaf(av[j], bf_lo(v[j].x), acc[0]);
            acc[1] = fmaf(av[j], bf_hi(v[j].x), acc[1]);
            acc[2] = fmaf(av[j], bf_lo(v[j].y), acc[2]);
            acc[3] = fmaf(av[j], bf_hi(v[j].y), acc[3]);
            acc[4] = fmaf(av[j], bf_lo(v[j].z), acc[4]);
            acc[5] = fmaf(av[j], bf_hi(v[j].z), acc[5]);
            acc[6] = fmaf(av[j], bf_lo(v[j].w), acc[6]);
            acc[7] = fmaf(av[j], bf_hi(v[j].w), acc[7]);
        }
        #pragma unroll
        for (int i = 0; i < 8; ++i)
            acc[i] += __shfl_xor(acc[i], 32, 64);

        floatx4 o;
        if (half == 0) { o.x = acc[0]; o.y = acc[1]; o.z = acc[2]; o.w = acc[3]; }
        else           { o.x = acc[4]; o.y = acc[5]; o.z = acc[6]; o.w = acc[7]; }
        __builtin_nontemporal_store(
            o, (floatx4*)&out[(size_t)n * HF + l32 * 8 + half * 4]);

        // rotate pipeline
        srcCur = srcNext; srcNext = srcN2;
        arCur  = arNext;  acCur   = acNext;
        n = n1;
    }
}

// ---------------------------------------------------------------------------
extern "C" void kernel_launch(void* const* d_in, const int* in_sizes, int n_in,
                              void* d_out, int out_size, void* d_ws, size_t ws_size,
                              hipStream_t stream) {
    // Inputs: row_ptr, col_ind, col_ptr, row_ind, feat, W, attn_l, attn_r
    const int*   col_ind = (const int*)  d_in[1];
    const float* feat    = (const float*)d_in[4];
    const float* W       = (const float*)d_in[5];
    const float* attn_l  = (const float*)d_in[6];
    const float* attn_r  = (const float*)d_in[7];
    float* out = (float*)d_out;

    const int N = in_sizes[0] - 1;   // 50000

    // ws: Hb bf16 [N*256] | arow f32 [N*4] | acol f32 [N*4] | Wt bf16 [64K]
    ushortT* Hb   = (ushortT*)d_ws;
    float*   arow = (float*)(Hb + (size_t)N * HF);
    float*   acol = arow + (size_t)N * NUM_HEADS;
    ushortT* Wt   = (ushortT*)(acol + (size_t)N * NUM_HEADS);

    conv_wt<<<256, 256, 0, stream>>>(W, Wt);

    dim3 ggrid((N + 63) / 64);
    gat_gemm_fused<<<ggrid, 256, 0, stream>>>(feat, Wt, attn_l, attn_r,
                                              Hb, arow, acol, N);

    // Persistent aggregation grid: 7 blocks/CU resident (launch_bounds cap).
    int nblocks = 7 * 256;                   // 1792
    int maxb = (N + 3) / 4;
    if (nblocks > maxb) nblocks = maxb;
    int NW = nblocks * 4;
    gat_aggregate6<<<nblocks, 256, 0, stream>>>(Hb, arow, acol, col_ind, out, N, NW);
}

// Round 5
// 334.893 us; speedup vs baseline: 1.0374x; 1.0374x over previous
//
#include <hip/hip_runtime.h>
#include <hip/hip_bf16.h>

#define DEG        16
#define IN_FEATS   256
#define NUM_HEADS  4
#define OUT_FEATS  64
#define HF         256
#define NEG_SLOPE  0.2f

#define CPITCH 264     // 256 + 8 (epilogue store-transpose pitch)

typedef __attribute__((ext_vector_type(8))) short  short8;
typedef __attribute__((ext_vector_type(4))) float  floatx4;
typedef unsigned short ushortT;

__device__ __forceinline__ unsigned short f2bf(float f) {
    union { float f; unsigned u; } v; v.f = f;
    unsigned r = v.u + 0x7fffu + ((v.u >> 16) & 1u);   // round-to-nearest-even
    return (unsigned short)(r >> 16);
}
// bf16 unpack: guaranteed 1 VALU each (shift / and)
__device__ __forceinline__ float bf_lo(unsigned u) {
    union { unsigned x; float f; } v; v.x = u << 16; return v.f;
}
__device__ __forceinline__ float bf_hi(unsigned u) {
    union { unsigned x; float f; } v; v.x = u & 0xffff0000u; return v.f;
}
// packed fp32x2 -> bf16x2 (manual RTNE pack; verified absmax since round 2)
__device__ __forceinline__ unsigned cvt2(float lo, float hi) {
    return (unsigned)f2bf(lo) | ((unsigned)f2bf(hi) << 16);
}

// ---------------------------------------------------------------------------
// Kernel 0: Wt[n][k] = bf16(W[k][n])  (256x256, tiny)
// ---------------------------------------------------------------------------
__global__ __launch_bounds__(256) void conv_wt(
    const float* __restrict__ W, ushortT* __restrict__ Wt)
{
    int n = blockIdx.x;
    int k = threadIdx.x;
    Wt[n * 256 + k] = f2bf(W[k * 256 + n]);
}

// ---------------------------------------------------------------------------
// Kernel 1: h = feat @ W via MFMA bf16 (BYTE-IDENTICAL to verified version).
// ---------------------------------------------------------------------------
__global__ __launch_bounds__(256, 3) void gat_gemm_fused(
    const float* __restrict__ feat,           // fp32 [M,256]
    const ushortT* __restrict__ Bt,           // Wt bf16 [n=256][k=256]
    const float* __restrict__ attn_l,         // [256]
    const float* __restrict__ attn_r,         // [256]
    ushortT* __restrict__ Hb,                 // h bf16 [M,256]
    float* __restrict__ arow,                 // [M,4]
    float* __restrict__ acol,                 // [M,4]
    int M)
{
    // As: 64 rows x 32 chunks x 16B = 32 KB (XOR-swizzled). Cs overlays.
    __shared__ __align__(16) ushortT SMEM[64 * CPITCH];
    ushortT* As = SMEM;
    ushortT* Cs = SMEM;

    const int tid  = threadIdx.x;
    const int wave = tid >> 6;       // == head
    const int lane = tid & 63;
    const int l15  = lane & 15;
    const int quad = lane >> 4;
    const int rowBase = blockIdx.x * 64;

    // ---- Prefetch B for ks=0 (independent of LDS staging).
    short8 bbuf[2][4];
    #pragma unroll
    for (int ni = 0; ni < 4; ++ni)
        bbuf[0][ni] = *(const short8*)&Bt[(wave * 64 + ni * 16 + l15) * 256 + quad * 8];

    // ---- Stage A: 64 rows x 256 cols fp32 -> bf16 swizzled LDS.
    #pragma unroll
    for (int pass = 0; pass < 2; ++pass) {
        float4 v[8];
        #pragma unroll
        for (int i = 0; i < 8; ++i) {
            int id  = pass * 2048 + i * 256 + tid;   // flat float4 index
            int row = id >> 6;                        // 64 float4 per row
            int c4  = id & 63;
            int gr  = rowBase + row; if (gr > M - 1) gr = M - 1;
            v[i] = *(const float4*)&feat[(size_t)gr * 256 + c4 * 4];
        }
        #pragma unroll
        for (int i = 0; i < 8; ++i) {
            int id   = pass * 2048 + i * 256 + tid;
            int row  = id >> 6;
            int c4   = id & 63;
            int cg   = c4 >> 1;                       // 16B chunk col (0..31)
            int half = c4 & 1;
            uint2 w = make_uint2(cvt2(v[i].x, v[i].y), cvt2(v[i].z, v[i].w));
            *(uint2*)&As[row * 256 + ((cg ^ (row & 7)) << 3) + half * 4] = w;
        }
    }

    __syncthreads();

    floatx4 acc[4][4] = {};

    #pragma unroll
    for (int ks = 0; ks < 8; ++ks) {
        if (ks < 7) {
            #pragma unroll
            for (int ni = 0; ni < 4; ++ni)
                bbuf[(ks + 1) & 1][ni] = *(const short8*)
                    &Bt[(wave * 64 + ni * 16 + l15) * 256 + (ks + 1) * 32 + quad * 8];
        }
        short8 af[4];
        #pragma unroll
        for (int mi = 0; mi < 4; ++mi) {
            int row = mi * 16 + l15;
            int q   = ks * 4 + quad;
            int cst = q ^ (row & 7);
            af[mi] = *(const short8*)&As[row * 256 + cst * 8];
        }
        #pragma unroll
        for (int mi = 0; mi < 4; ++mi)
            #pragma unroll
            for (int ni = 0; ni < 4; ++ni)
                acc[mi][ni] = __builtin_amdgcn_mfma_f32_16x16x32_bf16(
                    af[mi], bbuf[ks & 1][ni], acc[mi][ni], 0, 0, 0);
    }

    // ---- Epilogue A: attention scores (wave == head).
    float al[4], ar[4];
    #pragma unroll
    for (int ni = 0; ni < 4; ++ni) {
        al[ni] = attn_l[wave * 64 + ni * 16 + l15];
        ar[ni] = attn_r[wave * 64 + ni * 16 + l15];
    }
    #pragma unroll
    for (int mi = 0; mi < 4; ++mi) {
        #pragma unroll
        for (int reg = 0; reg < 4; ++reg) {
            float pl = 0.f, pr = 0.f;
            #pragma unroll
            for (int ni = 0; ni < 4; ++ni) {
                pl = fmaf(acc[mi][ni][reg], al[ni], pl);
                pr = fmaf(acc[mi][ni][reg], ar[ni], pr);
            }
            #pragma unroll
            for (int off = 8; off >= 1; off >>= 1) {
                pl += __shfl_xor(pl, off, 64);   // stays within 16-lane quad
                pr += __shfl_xor(pr, off, 64);
            }
            if (l15 == 0) {
                int gr = rowBase + mi * 16 + quad * 4 + reg;
                if (gr < M) {
                    arow[gr * NUM_HEADS + wave] = pl;
                    acol[gr * NUM_HEADS + wave] = pr;
                }
            }
        }
    }

    __syncthreads();   // all As reads complete before Cs overlay

    // ---- Epilogue B: h -> bf16, coalesced row-major store via LDS transpose.
    #pragma unroll
    for (int mi = 0; mi < 4; ++mi)
        #pragma unroll
        for (int ni = 0; ni < 4; ++ni)
            #pragma unroll
            for (int reg = 0; reg < 4; ++reg)
                Cs[(mi * 16 + quad * 4 + reg) * CPITCH + wave * 64 + ni * 16 + l15] =
                    f2bf(acc[mi][ni][reg]);
    __syncthreads();

    #pragma unroll
    for (int i = 0; i < 8; ++i) {
        int f  = tid + 256 * i;
        int r  = f >> 5;
        int c8 = (f & 31) << 3;
        int gr = rowBase + r;
        if (gr < M) {
            uint4 v = *(const uint4*)&Cs[r * CPITCH + c8];
            *(uint4*)&Hb[(size_t)gr * HF + c8] = v;
        }
    }
}

// ---------------------------------------------------------------------------
// Kernel 2 (v7): PERSISTENT GRID-STRIDE, 3-STAGE PIPELINE, PLAIN STORES.
// v6 post-mortem: nontemporal 16B/lane stores bypassed L2 write-combining ->
// WRITE_SIZE 50->417 MB (8x line amplification) + RMW fetch inflation
// (FETCH 197->527 MB).  Persistent structure itself WORKED: occupancy
// 43->72%.  v7 = v6 with plain L2-coalesced float4 stores (single-variable
// revert isolating the residency theory).
// Softmax math and lane mappings unchanged (verified v4/v5).
// ---------------------------------------------------------------------------
__global__ __launch_bounds__(256, 7) void gat_aggregate7(
    const ushortT* __restrict__ Hb,          // bf16 [N,256]
    const float* __restrict__ arow,          // [N,4]
    const float* __restrict__ acol,          // [N,4]
    const int* __restrict__ col_ind,         // [N*16]
    float* __restrict__ out,                 // [N,256] fp32
    int N, int NW)                            // NW = gridDim.x * 4 (total waves)
{
    const int tid  = threadIdx.x;
    const int wave = tid >> 6;
    const int lane = tid & 63;

    const int j16  = lane & 15;              // edge slot (softmax phase)
    const int hd16 = lane >> 4;              // head (softmax phase)
    const int l32     = lane & 31;           // feat chunk (agg phase)
    const int half    = lane >> 5;           // even/odd edge half
    const int headSel = (l32 >> 3) << 4;     // head*16 for alpha pull

    int n = blockIdx.x * 4 + wave;
    if (n >= N) return;

    // ---- Prologue: node n loads + node n+NW col_ind prefetch.
    int srcCur = col_ind[n * DEG + j16];
    int n1g    = n + NW;
    int srcNext = col_ind[((n1g < N) ? n1g : n) * DEG + j16];
    float arCur = arow[n * NUM_HEADS + hd16];
    float acCur = acol[srcCur * NUM_HEADS + hd16];

    while (n < N) {
        const int n1 = n + NW;
        const int n2 = n1 + NW;

        // S1: prefetch col_ind for n+2*NW (wave-uniform branch)
        int srcN2 = srcNext;
        if (n2 < N) srcN2 = col_ind[n2 * DEG + j16];

        // S2: prefetch scores for n+NW (srcNext loaded one iteration ago)
        float arNext = arCur, acNext = acCur;
        if (n1 < N) {
            arNext = arow[n1 * NUM_HEADS + hd16];
            acNext = acol[srcNext * NUM_HEADS + hd16];
        }

        // S3: softmax for node n (all operands already resident)
        float e = arCur + acCur;
        e = (e > 0.f) ? e : NEG_SLOPE * e;
        float m = e;
        #pragma unroll
        for (int off = 8; off >= 1; off >>= 1)
            m = fmaxf(m, __shfl_xor(m, off, 16));
        float ex = __expf(e - m);
        float s = ex;
        #pragma unroll
        for (int off = 8; off >= 1; off >>= 1)
            s += __shfl_xor(s, off, 16);
        float alpha = ex / s;                // alpha[head=hd16][edge=j16]

        // S4: dual-edge gather + FMA for node n.
        int   sj[8];
        float av[8];
        #pragma unroll
        for (int j = 0; j < 8; ++j) {
            int ep = (j << 1) + half;                     // edge 0..15
            sj[j] = __shfl(srcCur, ep, 64);
            av[j] = __shfl(alpha, headSel + ep, 64);
        }
        uint4 v[8];
        #pragma unroll
        for (int j = 0; j < 8; ++j)
            v[j] = *(const uint4*)&Hb[(size_t)sj[j] * HF + l32 * 8];

        __builtin_amdgcn_sched_barrier(0);   // keep all loads above the FMAs

        float acc[8] = {};
        #pragma unroll
        for (int j = 0; j < 8; ++j) {
            acc[0] = fmaf(av[j], bf_lo(v[j].x), acc[0]);
            acc[1] = fmaf(av[j], bf_hi(v[j].x), acc[1]);
            acc[2] = fmaf(av[j], bf_lo(v[j].y), acc[2]);
            acc[3] = fmaf(av[j], bf_hi(v[j].y), acc[3]);
            acc[4] = fmaf(av[j], bf_lo(v[j].z), acc[4]);
            acc[5] = fmaf(av[j], bf_hi(v[j].z), acc[5]);
            acc[6] = fmaf(av[j], bf_lo(v[j].w), acc[6]);
            acc[7] = fmaf(av[j], bf_hi(v[j].w), acc[7]);
        }
        #pragma unroll
        for (int i = 0; i < 8; ++i)
            acc[i] += __shfl_xor(acc[i], 32, 64);

        float4 o;
        if (half == 0) o = make_float4(acc[0], acc[1], acc[2], acc[3]);
        else           o = make_float4(acc[4], acc[5], acc[6], acc[7]);
        *(float4*)&out[(size_t)n * HF + l32 * 8 + half * 4] = o;

        // rotate pipeline
        srcCur = srcNext; srcNext = srcN2;
        arCur  = arNext;  acCur   = acNext;
        n = n1;
    }
}

// ---------------------------------------------------------------------------
extern "C" void kernel_launch(void* const* d_in, const int* in_sizes, int n_in,
                              void* d_out, int out_size, void* d_ws, size_t ws_size,
                              hipStream_t stream) {
    // Inputs: row_ptr, col_ind, col_ptr, row_ind, feat, W, attn_l, attn_r
    const int*   col_ind = (const int*)  d_in[1];
    const float* feat    = (const float*)d_in[4];
    const float* W       = (const float*)d_in[5];
    const float* attn_l  = (const float*)d_in[6];
    const float* attn_r  = (const float*)d_in[7];
    float* out = (float*)d_out;

    const int N = in_sizes[0] - 1;   // 50000

    // ws: Hb bf16 [N*256] | arow f32 [N*4] | acol f32 [N*4] | Wt bf16 [64K]
    ushortT* Hb   = (ushortT*)d_ws;
    float*   arow = (float*)(Hb + (size_t)N * HF);
    float*   acol = arow + (size_t)N * NUM_HEADS;
    ushortT* Wt   = (ushortT*)(acol + (size_t)N * NUM_HEADS);

    conv_wt<<<256, 256, 0, stream>>>(W, Wt);

    dim3 ggrid((N + 63) / 64);
    gat_gemm_fused<<<ggrid, 256, 0, stream>>>(feat, Wt, attn_l, attn_r,
                                              Hb, arow, acol, N);

    // Persistent aggregation grid: 7 blocks/CU resident (launch_bounds cap).
    int nblocks = 7 * 256;                   // 1792
    int maxb = (N + 3) / 4;
    if (nblocks > maxb) nblocks = maxb;
    int NW = nblocks * 4;
    gat_aggregate7<<<nblocks, 256, 0, stream>>>(Hb, arow, acol, col_ind, out, N, NW);
}

// Round 6
// 197.269 us; speedup vs baseline: 1.7611x; 1.6976x over previous
//
#include <hip/hip_runtime.h>
#include <hip/hip_bf16.h>

#define DEG        16
#define IN_FEATS   256
#define NUM_HEADS  4
#define OUT_FEATS  64
#define HF         256
#define NEG_SLOPE  0.2f

#define CPITCH 264     // 256 + 8 (epilogue store-transpose pitch)

typedef __attribute__((ext_vector_type(8))) short  short8;
typedef __attribute__((ext_vector_type(4))) float  floatx4;
typedef unsigned short ushortT;

__device__ __forceinline__ unsigned short f2bf(float f) {
    union { float f; unsigned u; } v; v.f = f;
    unsigned r = v.u + 0x7fffu + ((v.u >> 16) & 1u);   // round-to-nearest-even
    return (unsigned short)(r >> 16);
}
// bf16 unpack: guaranteed 1 VALU each (shift / and)
__device__ __forceinline__ float bf_lo(unsigned u) {
    union { unsigned x; float f; } v; v.x = u << 16; return v.f;
}
__device__ __forceinline__ float bf_hi(unsigned u) {
    union { unsigned x; float f; } v; v.x = u & 0xffff0000u; return v.f;
}
// packed fp32x2 -> bf16x2 (manual RTNE pack; verified absmax since round 2)
__device__ __forceinline__ unsigned cvt2(float lo, float hi) {
    return (unsigned)f2bf(lo) | ((unsigned)f2bf(hi) << 16);
}

// ---------------------------------------------------------------------------
// Kernel 0: Wt[n][k] = bf16(W[k][n])  (256x256, tiny)
// ---------------------------------------------------------------------------
__global__ __launch_bounds__(256) void conv_wt(
    const float* __restrict__ W, ushortT* __restrict__ Wt)
{
    int n = blockIdx.x;
    int k = threadIdx.x;
    Wt[n * 256 + k] = f2bf(W[k * 256 + n]);
}

// ---------------------------------------------------------------------------
// Kernel 1: h = feat @ W via MFMA bf16 (BYTE-IDENTICAL to verified version).
// ---------------------------------------------------------------------------
__global__ __launch_bounds__(256, 3) void gat_gemm_fused(
    const float* __restrict__ feat,           // fp32 [M,256]
    const ushortT* __restrict__ Bt,           // Wt bf16 [n=256][k=256]
    const float* __restrict__ attn_l,         // [256]
    const float* __restrict__ attn_r,         // [256]
    ushortT* __restrict__ Hb,                 // h bf16 [M,256]
    float* __restrict__ arow,                 // [M,4]
    float* __restrict__ acol,                 // [M,4]
    int M)
{
    // As: 64 rows x 32 chunks x 16B = 32 KB (XOR-swizzled). Cs overlays.
    __shared__ __align__(16) ushortT SMEM[64 * CPITCH];
    ushortT* As = SMEM;
    ushortT* Cs = SMEM;

    const int tid  = threadIdx.x;
    const int wave = tid >> 6;       // == head
    const int lane = tid & 63;
    const int l15  = lane & 15;
    const int quad = lane >> 4;
    const int rowBase = blockIdx.x * 64;

    // ---- Prefetch B for ks=0 (independent of LDS staging).
    short8 bbuf[2][4];
    #pragma unroll
    for (int ni = 0; ni < 4; ++ni)
        bbuf[0][ni] = *(const short8*)&Bt[(wave * 64 + ni * 16 + l15) * 256 + quad * 8];

    // ---- Stage A: 64 rows x 256 cols fp32 -> bf16 swizzled LDS.
    #pragma unroll
    for (int pass = 0; pass < 2; ++pass) {
        float4 v[8];
        #pragma unroll
        for (int i = 0; i < 8; ++i) {
            int id  = pass * 2048 + i * 256 + tid;   // flat float4 index
            int row = id >> 6;                        // 64 float4 per row
            int c4  = id & 63;
            int gr  = rowBase + row; if (gr > M - 1) gr = M - 1;
            v[i] = *(const float4*)&feat[(size_t)gr * 256 + c4 * 4];
        }
        #pragma unroll
        for (int i = 0; i < 8; ++i) {
            int id   = pass * 2048 + i * 256 + tid;
            int row  = id >> 6;
            int c4   = id & 63;
            int cg   = c4 >> 1;                       // 16B chunk col (0..31)
            int half = c4 & 1;
            uint2 w = make_uint2(cvt2(v[i].x, v[i].y), cvt2(v[i].z, v[i].w));
            *(uint2*)&As[row * 256 + ((cg ^ (row & 7)) << 3) + half * 4] = w;
        }
    }

    __syncthreads();

    floatx4 acc[4][4] = {};

    #pragma unroll
    for (int ks = 0; ks < 8; ++ks) {
        if (ks < 7) {
            #pragma unroll
            for (int ni = 0; ni < 4; ++ni)
                bbuf[(ks + 1) & 1][ni] = *(const short8*)
                    &Bt[(wave * 64 + ni * 16 + l15) * 256 + (ks + 1) * 32 + quad * 8];
        }
        short8 af[4];
        #pragma unroll
        for (int mi = 0; mi < 4; ++mi) {
            int row = mi * 16 + l15;
            int q   = ks * 4 + quad;
            int cst = q ^ (row & 7);
            af[mi] = *(const short8*)&As[row * 256 + cst * 8];
        }
        #pragma unroll
        for (int mi = 0; mi < 4; ++mi)
            #pragma unroll
            for (int ni = 0; ni < 4; ++ni)
                acc[mi][ni] = __builtin_amdgcn_mfma_f32_16x16x32_bf16(
                    af[mi], bbuf[ks & 1][ni], acc[mi][ni], 0, 0, 0);
    }

    // ---- Epilogue A: attention scores (wave == head).
    float al[4], ar[4];
    #pragma unroll
    for (int ni = 0; ni < 4; ++ni) {
        al[ni] = attn_l[wave * 64 + ni * 16 + l15];
        ar[ni] = attn_r[wave * 64 + ni * 16 + l15];
    }
    #pragma unroll
    for (int mi = 0; mi < 4; ++mi) {
        #pragma unroll
        for (int reg = 0; reg < 4; ++reg) {
            float pl = 0.f, pr = 0.f;
            #pragma unroll
            for (int ni = 0; ni < 4; ++ni) {
                pl = fmaf(acc[mi][ni][reg], al[ni], pl);
                pr = fmaf(acc[mi][ni][reg], ar[ni], pr);
            }
            #pragma unroll
            for (int off = 8; off >= 1; off >>= 1) {
                pl += __shfl_xor(pl, off, 64);   // stays within 16-lane quad
                pr += __shfl_xor(pr, off, 64);
            }
            if (l15 == 0) {
                int gr = rowBase + mi * 16 + quad * 4 + reg;
                if (gr < M) {
                    arow[gr * NUM_HEADS + wave] = pl;
                    acol[gr * NUM_HEADS + wave] = pr;
                }
            }
        }
    }

    __syncthreads();   // all As reads complete before Cs overlay

    // ---- Epilogue B: h -> bf16, coalesced row-major store via LDS transpose.
    #pragma unroll
    for (int mi = 0; mi < 4; ++mi)
        #pragma unroll
        for (int ni = 0; ni < 4; ++ni)
            #pragma unroll
            for (int reg = 0; reg < 4; ++reg)
                Cs[(mi * 16 + quad * 4 + reg) * CPITCH + wave * 64 + ni * 16 + l15] =
                    f2bf(acc[mi][ni][reg]);
    __syncthreads();

    #pragma unroll
    for (int i = 0; i < 8; ++i) {
        int f  = tid + 256 * i;
        int r  = f >> 5;
        int c8 = (f & 31) << 3;
        int gr = rowBase + r;
        if (gr < M) {
            uint4 v = *(const uint4*)&Cs[r * CPITCH + c8];
            *(uint4*)&Hb[(size_t)gr * HF + c8] = v;
        }
    }
}

// ---------------------------------------------------------------------------
// Kernel 2 (v8): PERSISTENT GRID + 3-STAGE PIPELINE, NO FORCED OCCUPANCY.
// v7 post-mortem: WRITE_SIZE stayed 379 MB with plain stores -> amplification
// was NEVER the store; it was SCRATCH SPILL.  __launch_bounds__(256,7)
// capped VGPRs (observed 36 < the ~48 the gather batch needs) -> v[8]
// spilled -> 400 MB scratch write + read per pass.  v5 proved the same
// batch fits at 44 VGPR without the constraint.
// v8 = v7 minus the min-waves clause (register allocator free), grid 2048
// blocks (8/CU at <=64 VGPR).  Single-variable fix isolating the residency
// theory at last.
// ---------------------------------------------------------------------------
__global__ __launch_bounds__(256) void gat_aggregate8(
    const ushortT* __restrict__ Hb,          // bf16 [N,256]
    const float* __restrict__ arow,          // [N,4]
    const float* __restrict__ acol,          // [N,4]
    const int* __restrict__ col_ind,         // [N*16]
    float* __restrict__ out,                 // [N,256] fp32
    int N, int NW)                            // NW = gridDim.x * 4 (total waves)
{
    const int tid  = threadIdx.x;
    const int wave = tid >> 6;
    const int lane = tid & 63;

    const int j16  = lane & 15;              // edge slot (softmax phase)
    const int hd16 = lane >> 4;              // head (softmax phase)
    const int l32     = lane & 31;           // feat chunk (agg phase)
    const int half    = lane >> 5;           // even/odd edge half
    const int headSel = (l32 >> 3) << 4;     // head*16 for alpha pull

    int n = blockIdx.x * 4 + wave;
    if (n >= N) return;

    // ---- Prologue: node n loads + node n+NW col_ind prefetch.
    int srcCur = col_ind[n * DEG + j16];
    int n1g    = n + NW;
    int srcNext = col_ind[((n1g < N) ? n1g : n) * DEG + j16];
    float arCur = arow[n * NUM_HEADS + hd16];
    float acCur = acol[srcCur * NUM_HEADS + hd16];

    while (n < N) {
        const int n1 = n + NW;
        const int n2 = n1 + NW;

        // S1: prefetch col_ind for n+2*NW (wave-uniform branch)
        int srcN2 = srcNext;
        if (n2 < N) srcN2 = col_ind[n2 * DEG + j16];

        // S2: prefetch scores for n+NW (srcNext loaded one iteration ago)
        float arNext = arCur, acNext = acCur;
        if (n1 < N) {
            arNext = arow[n1 * NUM_HEADS + hd16];
            acNext = acol[srcNext * NUM_HEADS + hd16];
        }

        // S3: softmax for node n (all operands already resident)
        float e = arCur + acCur;
        e = (e > 0.f) ? e : NEG_SLOPE * e;
        float m = e;
        #pragma unroll
        for (int off = 8; off >= 1; off >>= 1)
            m = fmaxf(m, __shfl_xor(m, off, 16));
        float ex = __expf(e - m);
        float s = ex;
        #pragma unroll
        for (int off = 8; off >= 1; off >>= 1)
            s += __shfl_xor(s, off, 16);
        float alpha = ex / s;                // alpha[head=hd16][edge=j16]

        // S4: dual-edge gather + FMA for node n.
        int   sj[8];
        float av[8];
        #pragma unroll
        for (int j = 0; j < 8; ++j) {
            int ep = (j << 1) + half;                     // edge 0..15
            sj[j] = __shfl(srcCur, ep, 64);
            av[j] = __shfl(alpha, headSel + ep, 64);
        }
        uint4 v[8];
        #pragma unroll
        for (int j = 0; j < 8; ++j)
            v[j] = *(const uint4*)&Hb[(size_t)sj[j] * HF + l32 * 8];

        __builtin_amdgcn_sched_barrier(0);   // keep all loads above the FMAs

        float acc[8] = {};
        #pragma unroll
        for (int j = 0; j < 8; ++j) {
            acc[0] = fmaf(av[j], bf_lo(v[j].x), acc[0]);
            acc[1] = fmaf(av[j], bf_hi(v[j].x), acc[1]);
            acc[2] = fmaf(av[j], bf_lo(v[j].y), acc[2]);
            acc[3] = fmaf(av[j], bf_hi(v[j].y), acc[3]);
            acc[4] = fmaf(av[j], bf_lo(v[j].z), acc[4]);
            acc[5] = fmaf(av[j], bf_hi(v[j].z), acc[5]);
            acc[6] = fmaf(av[j], bf_lo(v[j].w), acc[6]);
            acc[7] = fmaf(av[j], bf_hi(v[j].w), acc[7]);
        }
        #pragma unroll
        for (int i = 0; i < 8; ++i)
            acc[i] += __shfl_xor(acc[i], 32, 64);

        float4 o;
        if (half == 0) o = make_float4(acc[0], acc[1], acc[2], acc[3]);
        else           o = make_float4(acc[4], acc[5], acc[6], acc[7]);
        *(float4*)&out[(size_t)n * HF + l32 * 8 + half * 4] = o;

        // rotate pipeline
        srcCur = srcNext; srcNext = srcN2;
        arCur  = arNext;  acCur   = acNext;
        n = n1;
    }
}

// ---------------------------------------------------------------------------
extern "C" void kernel_launch(void* const* d_in, const int* in_sizes, int n_in,
                              void* d_out, int out_size, void* d_ws, size_t ws_size,
                              hipStream_t stream) {
    // Inputs: row_ptr, col_ind, col_ptr, row_ind, feat, W, attn_l, attn_r
    const int*   col_ind = (const int*)  d_in[1];
    const float* feat    = (const float*)d_in[4];
    const float* W       = (const float*)d_in[5];
    const float* attn_l  = (const float*)d_in[6];
    const float* attn_r  = (const float*)d_in[7];
    float* out = (float*)d_out;

    const int N = in_sizes[0] - 1;   // 50000

    // ws: Hb bf16 [N*256] | arow f32 [N*4] | acol f32 [N*4] | Wt bf16 [64K]
    ushortT* Hb   = (ushortT*)d_ws;
    float*   arow = (float*)(Hb + (size_t)N * HF);
    float*   acol = arow + (size_t)N * NUM_HEADS;
    ushortT* Wt   = (ushortT*)(acol + (size_t)N * NUM_HEADS);

    conv_wt<<<256, 256, 0, stream>>>(W, Wt);

    dim3 ggrid((N + 63) / 64);
    gat_gemm_fused<<<ggrid, 256, 0, stream>>>(feat, Wt, attn_l, attn_r,
                                              Hb, arow, acol, N);

    // Persistent aggregation grid: 8 blocks/CU (no launch_bounds min-wave
    // clause -> register allocator free; v5 showed the batch fits at 44).
    int nblocks = 8 * 256;                   // 2048
    int maxb = (N + 3) / 4;
    if (nblocks > maxb) nblocks = maxb;
    int NW = nblocks * 4;
    gat_aggregate8<<<nblocks, 256, 0, stream>>>(Hb, arow, acol, col_ind, out, N, NW);
}

// Round 7
// 190.633 us; speedup vs baseline: 1.8224x; 1.0348x over previous
//
#include <hip/hip_runtime.h>
#include <hip/hip_bf16.h>

#define DEG        16
#define IN_FEATS   256
#define NUM_HEADS  4
#define OUT_FEATS  64
#define HF         256
#define NEG_SLOPE  0.2f

#define CPITCH 264     // 256 + 8 (epilogue store-transpose pitch)

typedef __attribute__((ext_vector_type(8))) short  short8;
typedef __attribute__((ext_vector_type(4))) float  floatx4;
typedef unsigned short ushortT;

__device__ __forceinline__ unsigned short f2bf(float f) {
    union { float f; unsigned u; } v; v.f = f;
    unsigned r = v.u + 0x7fffu + ((v.u >> 16) & 1u);   // round-to-nearest-even
    return (unsigned short)(r >> 16);
}
// bf16 unpack: guaranteed 1 VALU each (shift / and)
__device__ __forceinline__ float bf_lo(unsigned u) {
    union { unsigned x; float f; } v; v.x = u << 16; return v.f;
}
__device__ __forceinline__ float bf_hi(unsigned u) {
    union { unsigned x; float f; } v; v.x = u & 0xffff0000u; return v.f;
}
// packed fp32x2 -> bf16x2 (manual RTNE pack; verified absmax since round 2)
__device__ __forceinline__ unsigned cvt2(float lo, float hi) {
    return (unsigned)f2bf(lo) | ((unsigned)f2bf(hi) << 16);
}

// ---------------------------------------------------------------------------
// Kernel 0: Wt[n][k] = bf16(W[k][n])  (256x256, tiny)
// ---------------------------------------------------------------------------
__global__ __launch_bounds__(256) void conv_wt(
    const float* __restrict__ W, ushortT* __restrict__ Wt)
{
    int n = blockIdx.x;
    int k = threadIdx.x;
    Wt[n * 256 + k] = f2bf(W[k * 256 + n]);
}

// ---------------------------------------------------------------------------
// Kernel 1: h = feat @ W via MFMA bf16 (BYTE-IDENTICAL to verified version).
// ---------------------------------------------------------------------------
__global__ __launch_bounds__(256, 3) void gat_gemm_fused(
    const float* __restrict__ feat,           // fp32 [M,256]
    const ushortT* __restrict__ Bt,           // Wt bf16 [n=256][k=256]
    const float* __restrict__ attn_l,         // [256]
    const float* __restrict__ attn_r,         // [256]
    ushortT* __restrict__ Hb,                 // h bf16 [M,256]
    float* __restrict__ arow,                 // [M,4]
    float* __restrict__ acol,                 // [M,4]
    int M)
{
    // As: 64 rows x 32 chunks x 16B = 32 KB (XOR-swizzled). Cs overlays.
    __shared__ __align__(16) ushortT SMEM[64 * CPITCH];
    ushortT* As = SMEM;
    ushortT* Cs = SMEM;

    const int tid  = threadIdx.x;
    const int wave = tid >> 6;       // == head
    const int lane = tid & 63;
    const int l15  = lane & 15;
    const int quad = lane >> 4;
    const int rowBase = blockIdx.x * 64;

    // ---- Prefetch B for ks=0 (independent of LDS staging).
    short8 bbuf[2][4];
    #pragma unroll
    for (int ni = 0; ni < 4; ++ni)
        bbuf[0][ni] = *(const short8*)&Bt[(wave * 64 + ni * 16 + l15) * 256 + quad * 8];

    // ---- Stage A: 64 rows x 256 cols fp32 -> bf16 swizzled LDS.
    #pragma unroll
    for (int pass = 0; pass < 2; ++pass) {
        float4 v[8];
        #pragma unroll
        for (int i = 0; i < 8; ++i) {
            int id  = pass * 2048 + i * 256 + tid;   // flat float4 index
            int row = id >> 6;                        // 64 float4 per row
            int c4  = id & 63;
            int gr  = rowBase + row; if (gr > M - 1) gr = M - 1;
            v[i] = *(const float4*)&feat[(size_t)gr * 256 + c4 * 4];
        }
        #pragma unroll
        for (int i = 0; i < 8; ++i) {
            int id   = pass * 2048 + i * 256 + tid;
            int row  = id >> 6;
            int c4   = id & 63;
            int cg   = c4 >> 1;                       // 16B chunk col (0..31)
            int half = c4 & 1;
            uint2 w = make_uint2(cvt2(v[i].x, v[i].y), cvt2(v[i].z, v[i].w));
            *(uint2*)&As[row * 256 + ((cg ^ (row & 7)) << 3) + half * 4] = w;
        }
    }

    __syncthreads();

    floatx4 acc[4][4] = {};

    #pragma unroll
    for (int ks = 0; ks < 8; ++ks) {
        if (ks < 7) {
            #pragma unroll
            for (int ni = 0; ni < 4; ++ni)
                bbuf[(ks + 1) & 1][ni] = *(const short8*)
                    &Bt[(wave * 64 + ni * 16 + l15) * 256 + (ks + 1) * 32 + quad * 8];
        }
        short8 af[4];
        #pragma unroll
        for (int mi = 0; mi < 4; ++mi) {
            int row = mi * 16 + l15;
            int q   = ks * 4 + quad;
            int cst = q ^ (row & 7);
            af[mi] = *(const short8*)&As[row * 256 + cst * 8];
        }
        #pragma unroll
        for (int mi = 0; mi < 4; ++mi)
            #pragma unroll
            for (int ni = 0; ni < 4; ++ni)
                acc[mi][ni] = __builtin_amdgcn_mfma_f32_16x16x32_bf16(
                    af[mi], bbuf[ks & 1][ni], acc[mi][ni], 0, 0, 0);
    }

    // ---- Epilogue A: attention scores (wave == head).
    float al[4], ar[4];
    #pragma unroll
    for (int ni = 0; ni < 4; ++ni) {
        al[ni] = attn_l[wave * 64 + ni * 16 + l15];
        ar[ni] = attn_r[wave * 64 + ni * 16 + l15];
    }
    #pragma unroll
    for (int mi = 0; mi < 4; ++mi) {
        #pragma unroll
        for (int reg = 0; reg < 4; ++reg) {
            float pl = 0.f, pr = 0.f;
            #pragma unroll
            for (int ni = 0; ni < 4; ++ni) {
                pl = fmaf(acc[mi][ni][reg], al[ni], pl);
                pr = fmaf(acc[mi][ni][reg], ar[ni], pr);
            }
            #pragma unroll
            for (int off = 8; off >= 1; off >>= 1) {
                pl += __shfl_xor(pl, off, 64);   // stays within 16-lane quad
                pr += __shfl_xor(pr, off, 64);
            }
            if (l15 == 0) {
                int gr = rowBase + mi * 16 + quad * 4 + reg;
                if (gr < M) {
                    arow[gr * NUM_HEADS + wave] = pl;
                    acol[gr * NUM_HEADS + wave] = pr;
                }
            }
        }
    }

    __syncthreads();   // all As reads complete before Cs overlay

    // ---- Epilogue B: h -> bf16, coalesced row-major store via LDS transpose.
    #pragma unroll
    for (int mi = 0; mi < 4; ++mi)
        #pragma unroll
        for (int ni = 0; ni < 4; ++ni)
            #pragma unroll
            for (int reg = 0; reg < 4; ++reg)
                Cs[(mi * 16 + quad * 4 + reg) * CPITCH + wave * 64 + ni * 16 + l15] =
                    f2bf(acc[mi][ni][reg]);
    __syncthreads();

    #pragma unroll
    for (int i = 0; i < 8; ++i) {
        int f  = tid + 256 * i;
        int r  = f >> 5;
        int c8 = (f & 31) << 3;
        int gr = rowBase + r;
        if (gr < M) {
            uint4 v = *(const uint4*)&Cs[r * CPITCH + c8];
            *(uint4*)&Hb[(size_t)gr * HF + c8] = v;
        }
    }
}

// ---------------------------------------------------------------------------
// Kernel 2 (v9): TWO NODES PER WAVE, 16 GATHERS IN FLIGHT.
// v8 post-mortem: dur invariant (65-67 us) across churn/batch/persistent
// variants -> structure-insensitive, memory-system-limited.  L2 hit 52% is
// at its REUSE ceiling (~2 touches/line/XCD); beyond-L2 path runs at
// 3.7 TB/s vs 4.5 TB/s observed on the same path (v6 spill traffic).
// Last concurrency knob: double per-wave MLP.  Each wave processes nodes
// 2w and 2w+1: both softmaxes up front, all 16 gather loads issued
// back-to-back, FMA A overlaps the tail of B's loads.
// Per-node lane math is byte-identical to verified v4.
// Spill canary: WRITE_SIZE must stay 50 MB (VGPR ~110-125 expected).
// ---------------------------------------------------------------------------
__global__ __launch_bounds__(256) void gat_aggregate9(
    const ushortT* __restrict__ Hb,          // bf16 [N,256]
    const float* __restrict__ arow,          // [N,4]
    const float* __restrict__ acol,          // [N,4]
    const int* __restrict__ col_ind,         // [N*16]
    float* __restrict__ out,                 // [N,256] fp32
    int N)
{
    const int tid  = threadIdx.x;
    const int wave = tid >> 6;
    const int lane = tid & 63;
    const int gw   = blockIdx.x * 4 + wave;   // global wave id

    int nA = gw * 2;
    if (nA >= N) return;
    int nB = nA + 1;
    const bool hasB = (nB < N);
    if (!hasB) nB = nA;                       // safe duplicate, store guarded

    const int j16  = lane & 15;
    const int hd16 = lane >> 4;

    // ---- Softmax for both nodes (lane = head*16 + edge, verified layout).
    int srcA = col_ind[nA * DEG + j16];
    int srcB = col_ind[nB * DEG + j16];
    float eA = arow[nA * NUM_HEADS + hd16] + acol[srcA * NUM_HEADS + hd16];
    float eB = arow[nB * NUM_HEADS + hd16] + acol[srcB * NUM_HEADS + hd16];
    eA = (eA > 0.f) ? eA : NEG_SLOPE * eA;
    eB = (eB > 0.f) ? eB : NEG_SLOPE * eB;

    float mA = eA, mB = eB;
    #pragma unroll
    for (int off = 8; off >= 1; off >>= 1) {
        mA = fmaxf(mA, __shfl_xor(mA, off, 16));
        mB = fmaxf(mB, __shfl_xor(mB, off, 16));
    }
    float exA = __expf(eA - mA), exB = __expf(eB - mB);
    float sA = exA, sB = exB;
    #pragma unroll
    for (int off = 8; off >= 1; off >>= 1) {
        sA += __shfl_xor(sA, off, 16);
        sB += __shfl_xor(sB, off, 16);
    }
    float alA = exA / sA;                    // alpha[head=hd16][edge=j16]
    float alB = exB / sB;

    // ---- Aggregation: dual-edge layout per node (verified v4 mapping).
    const int l32     = lane & 31;
    const int half    = lane >> 5;
    const int headSel = (l32 >> 3) << 4;

    int   sjA[8], sjB[8];
    float avA[8], avB[8];
    #pragma unroll
    for (int j = 0; j < 8; ++j) {
        int ep = (j << 1) + half;                     // edge 0..15
        sjA[j] = __shfl(srcA, ep, 64);
        avA[j] = __shfl(alA, headSel + ep, 64);
        sjB[j] = __shfl(srcB, ep, 64);
        avB[j] = __shfl(alB, headSel + ep, 64);
    }

    // 16 loads issued back-to-back: 16 outstanding misses per wave.
    uint4 vA[8], vB[8];
    #pragma unroll
    for (int j = 0; j < 8; ++j)
        vA[j] = *(const uint4*)&Hb[(size_t)sjA[j] * HF + l32 * 8];
    #pragma unroll
    for (int j = 0; j < 8; ++j)
        vB[j] = *(const uint4*)&Hb[(size_t)sjB[j] * HF + l32 * 8];

    __builtin_amdgcn_sched_barrier(0);   // loads may not sink below

    float accA[8] = {}, accB[8] = {};
    #pragma unroll
    for (int j = 0; j < 8; ++j) {
        accA[0] = fmaf(avA[j], bf_lo(vA[j].x), accA[0]);
        accA[1] = fmaf(avA[j], bf_hi(vA[j].x), accA[1]);
        accA[2] = fmaf(avA[j], bf_lo(vA[j].y), accA[2]);
        accA[3] = fmaf(avA[j], bf_hi(vA[j].y), accA[3]);
        accA[4] = fmaf(avA[j], bf_lo(vA[j].z), accA[4]);
        accA[5] = fmaf(avA[j], bf_hi(vA[j].z), accA[5]);
        accA[6] = fmaf(avA[j], bf_lo(vA[j].w), accA[6]);
        accA[7] = fmaf(avA[j], bf_hi(vA[j].w), accA[7]);
    }
    #pragma unroll
    for (int j = 0; j < 8; ++j) {
        accB[0] = fmaf(avB[j], bf_lo(vB[j].x), accB[0]);
        accB[1] = fmaf(avB[j], bf_hi(vB[j].x), accB[1]);
        accB[2] = fmaf(avB[j], bf_lo(vB[j].y), accB[2]);
        accB[3] = fmaf(avB[j], bf_hi(vB[j].y), accB[3]);
        accB[4] = fmaf(avB[j], bf_lo(vB[j].z), accB[4]);
        accB[5] = fmaf(avB[j], bf_hi(vB[j].z), accB[5]);
        accB[6] = fmaf(avB[j], bf_lo(vB[j].w), accB[6]);
        accB[7] = fmaf(avB[j], bf_hi(vB[j].w), accB[7]);
    }

    #pragma unroll
    for (int i = 0; i < 8; ++i) {
        accA[i] += __shfl_xor(accA[i], 32, 64);
        accB[i] += __shfl_xor(accB[i], 32, 64);
    }

    float4 oA, oB;
    if (half == 0) {
        oA = make_float4(accA[0], accA[1], accA[2], accA[3]);
        oB = make_float4(accB[0], accB[1], accB[2], accB[3]);
    } else {
        oA = make_float4(accA[4], accA[5], accA[6], accA[7]);
        oB = make_float4(accB[4], accB[5], accB[6], accB[7]);
    }
    *(float4*)&out[(size_t)nA * HF + l32 * 8 + half * 4] = oA;
    if (hasB)
        *(float4*)&out[(size_t)nB * HF + l32 * 8 + half * 4] = oB;
}

// ---------------------------------------------------------------------------
extern "C" void kernel_launch(void* const* d_in, const int* in_sizes, int n_in,
                              void* d_out, int out_size, void* d_ws, size_t ws_size,
                              hipStream_t stream) {
    // Inputs: row_ptr, col_ind, col_ptr, row_ind, feat, W, attn_l, attn_r
    const int*   col_ind = (const int*)  d_in[1];
    const float* feat    = (const float*)d_in[4];
    const float* W       = (const float*)d_in[5];
    const float* attn_l  = (const float*)d_in[6];
    const float* attn_r  = (const float*)d_in[7];
    float* out = (float*)d_out;

    const int N = in_sizes[0] - 1;   // 50000

    // ws: Hb bf16 [N*256] | arow f32 [N*4] | acol f32 [N*4] | Wt bf16 [64K]
    ushortT* Hb   = (ushortT*)d_ws;
    float*   arow = (float*)(Hb + (size_t)N * HF);
    float*   acol = arow + (size_t)N * NUM_HEADS;
    ushortT* Wt   = (ushortT*)(acol + (size_t)N * NUM_HEADS);

    conv_wt<<<256, 256, 0, stream>>>(W, Wt);

    dim3 ggrid((N + 63) / 64);
    gat_gemm_fused<<<ggrid, 256, 0, stream>>>(feat, Wt, attn_l, attn_r,
                                              Hb, arow, acol, N);

    // 2 nodes per wave, 8 nodes per block.
    gat_aggregate9<<<(N + 7) / 8, 256, 0, stream>>>(Hb, arow, acol, col_ind, out, N);
}